// Round 1
// baseline (252.379 us; speedup 1.0000x reference)
//
#include <hip/hip_runtime.h>
#include <hip/hip_bf16.h>
#include <math.h>

#define NHEAD 16
#define HD 64
#define TSEQ 2048
#define CEMB 1024

typedef __attribute__((ext_vector_type(8))) short short8;
typedef __attribute__((ext_vector_type(4))) float f32x4;
typedef __attribute__((ext_vector_type(16))) float f32x16;

__device__ inline unsigned short f2bf(float f) {
  union { float f; unsigned u; } x; x.f = f;
  unsigned r = x.u + 0x7FFFu + ((x.u >> 16) & 1u);
  return (unsigned short)(r >> 16);
}

__device__ inline unsigned pk2(float a, float b) {
  __hip_bfloat162 t = __float22bfloat162_rn(make_float2(a, b));  // low=a, high=b
  union { __hip_bfloat162 v; unsigned u; } c; c.v = t;
  return c.u;
}

// raw 2^x (v_exp_f32), no libm wrapper, no extra mul
__device__ inline float ex2(float x) {
#if __has_builtin(__builtin_amdgcn_exp2f)
  return __builtin_amdgcn_exp2f(x);
#else
  float r; asm("v_exp_f32 %0, %1" : "=v"(r) : "v"(x)); return r;
#endif
}

__device__ inline void gload16(const void* g, void* l) {
  __builtin_amdgcn_global_load_lds(
      (const __attribute__((address_space(1))) unsigned int*)g,
      (__attribute__((address_space(3))) unsigned int*)l, 16, 0, 0);
}

// ---------- cast x fp32 -> bf16 ----------
__global__ __launch_bounds__(256) void castx(const float* __restrict__ in,
                                             unsigned short* __restrict__ out) {
  int i = blockIdx.x * 256 + threadIdx.x;
  float4 v = ((const float4*)in)[i];
  ushort4 o;
  o.x = f2bf(v.x); o.y = f2bf(v.y); o.z = f2bf(v.z); o.w = f2bf(v.w);
  ((ushort4*)out)[i] = o;
}

// ---------- transpose W [1024][N] fp32 -> Wt [N][1024] bf16 ----------
__global__ __launch_bounds__(256) void transW(const float* __restrict__ W,
                                              unsigned short* __restrict__ Wt,
                                              int N) {
  __shared__ float t[64][65];
  const int tid = threadIdx.x;
  const int rb = blockIdx.y * 64;
  const int cb = blockIdx.x * 64;
#pragma unroll
  for (int i = 0; i < 16; ++i) {
    int idx = i * 256 + tid, r = idx >> 6, cl = idx & 63;
    t[r][cl] = W[(size_t)(rb + r) * N + cb + cl];
  }
  __syncthreads();
#pragma unroll
  for (int i = 0; i < 16; ++i) {
    int idx = i * 256 + tid, r = idx >> 6, cl = idx & 63;
    Wt[(size_t)(cb + r) * 1024 + rb + cl] = f2bf(t[cl][r]);
  }
}

// ---------- MFMA GEMM 128x128, BK=64, global_load_lds + XOR swizzle ----------
template <int MODE>
__global__ __launch_bounds__(256) void mm128(const unsigned short* __restrict__ A,
                                             const unsigned short* __restrict__ Bt,
                                             const float* __restrict__ bias,
                                             void* __restrict__ out0,
                                             unsigned short* __restrict__ ko,
                                             unsigned short* __restrict__ vto) {
  __shared__ __align__(16) unsigned char Asm[16384];
  __shared__ __align__(16) unsigned char Bsm[16384];
  const int tid = threadIdx.x;
  const int lane = tid & 63;
  const int w = tid >> 6;
  const int wm = w >> 1, wn = w & 1;
  const int c = lane & 15, g = lane >> 4;
  const int rowbase = blockIdx.y * 128;
  const int colbase = blockIdx.x * 128;

  f32x4 acc[4][4];
#pragma unroll
  for (int m = 0; m < 4; ++m)
#pragma unroll
    for (int n = 0; n < 4; ++n) acc[m][n] = (f32x4){0.f, 0.f, 0.f, 0.f};

  const unsigned char* Ab = (const unsigned char*)(A + (size_t)rowbase * 1024);
  const unsigned char* Bb = (const unsigned char*)(Bt + (size_t)colbase * 1024);
  const int swz = (c & 7) << 4;

  for (int kt = 0; kt < 16; ++kt) {
    __syncthreads();
#pragma unroll
    for (int it = 0; it < 4; ++it) {
      const int L = it * 4096 + tid * 16;
      const int row = L >> 7;
      const int sc = (L & 127) ^ ((row & 7) << 4);
      gload16(Ab + (size_t)row * 2048 + kt * 128 + sc, Asm + L);
      gload16(Bb + (size_t)row * 2048 + kt * 128 + sc, Bsm + L);
    }
    __syncthreads();
#pragma unroll
    for (int ks = 0; ks < 2; ++ks) {
      const int cb = ks * 64 + 16 * g;
      short8 af[4], bf[4];
#pragma unroll
      for (int m = 0; m < 4; ++m)
        af[m] = *(const short8*)(Asm + (wm * 64 + m * 16 + c) * 128 + (cb ^ swz));
#pragma unroll
      for (int n = 0; n < 4; ++n)
        bf[n] = *(const short8*)(Bsm + (wn * 64 + n * 16 + c) * 128 + (cb ^ swz));
#pragma unroll
      for (int m = 0; m < 4; ++m)
#pragma unroll
        for (int n = 0; n < 4; ++n)
          acc[m][n] = __builtin_amdgcn_mfma_f32_16x16x32_bf16(af[m], bf[n], acc[m][n], 0, 0, 0);
    }
  }

#pragma unroll
  for (int m = 0; m < 4; ++m) {
    const int rw = rowbase + wm * 64 + m * 16 + 4 * g;
#pragma unroll
    for (int n = 0; n < 4; ++n) {
      const int col = colbase + wn * 64 + n * 16 + c;
      const float bz = bias[col];
      if (MODE == 0) {
        unsigned short* qo = (unsigned short*)out0;
        const int sel = col >> 10, cc = col & 1023, hh = cc >> 6, d = cc & 63;
#pragma unroll
        for (int r = 0; r < 4; ++r) {
          const int row = rw + r;
          const int b = row >> 11, t = row & 2047;
          const float val = acc[m][n][r] + bz;
          const size_t bh = (size_t)(b * NHEAD + hh);
          if (sel == 0)
            // 0.125 * log2(e): scores arrive in log2 domain for raw v_exp_f32
            qo[(bh * TSEQ + t) * HD + d] = f2bf(val * 0.18033688011112042f);
          else if (sel == 1)
            ko[(bh * TSEQ + t) * HD + d] = f2bf(val);
          else
            vto[(bh * HD + d) * TSEQ + t] = f2bf(val);
        }
      } else {
        float* out = (float*)out0;
#pragma unroll
        for (int r = 0; r < 4; ++r)
          out[(size_t)(rw + r) * 1024 + col] = acc[m][n][r] + bz;
      }
    }
  }
}

// ---------- LIF attention, swapped-operand 32x32 in-register softmax ----------
// Block = 256 thr = 4 waves = 4 KV-splits of one 32-query tile.
// S^T = mfma(K, Q^T): lane owns query col (lane&31), 16 keys in regs.
// Scores are in log2 domain (Q pre-scaled by 0.125*log2e) -> raw v_exp_f32.
// The softmax normalizer li is folded out: accumulate m' = e*w, ms' = sum m';
// y = O'/ms' is invariant to li (epsilon 1e-8 negligible at these magnitudes).
// Split combine via LDS ds_add_f32 atomics into a single [2][32][33] buffer
// (9.5 KB LDS vs 34.8 KB before -> occupancy cap 50% -> 75%).
__global__ __launch_bounds__(256) void lif_sw(
    const unsigned short* __restrict__ qb,   // [BH][T][64] bf16, pre-scaled 0.125*log2e
    const unsigned short* __restrict__ kb,   // [BH][T][64] bf16
    const unsigned short* __restrict__ vtb,  // [BH][64][T] bf16
    const float* __restrict__ thr_p, const float* __restrict__ leak_p,
    const float* __restrict__ steep_p,
    unsigned short* __restrict__ y) {        // [B][T][1024] bf16
  __shared__ float obuf[2][32][33];          // accumulated O^T partials, 8.4 KB
  __shared__ float lbuf[4][32];
  __shared__ float msbuf[4][32];

  const int bh = blockIdx.x;
  const int qt = 63 - blockIdx.y;            // 32-row q tiles, big first
  const int h = bh & (NHEAD - 1);
  const int b = bh >> 4;
  const int tid = threadIdx.x;
  const int s = tid >> 6;                    // kv split 0..3
  const int lane = tid & 63;
  const int qv = lane & 31;                  // query col
  const int hi = lane >> 5;
  const int klb = 4 * hi;
  const int qbase = qt * 32;

  const int nt = qt + 1;
  const int nt4 = (nt + 3) >> 2;
  const int t0 = s * nt4;
  const int t1 = min(t0 + nt4, nt);

  const unsigned short* qp = qb + (size_t)bh * TSEQ * HD;
  const unsigned short* kp = kb + (size_t)bh * TSEQ * HD;
  const unsigned short* vp = vtb + (size_t)bh * HD * TSEQ;

  // zero the shared O accumulator (ordered before use by the pass-A barrier)
  for (int i = tid; i < 2 * 32 * 33; i += 256) ((float*)obuf)[i] = 0.f;

  const float thr = fabsf(thr_p[h]) * 0.1f;
  const float lk = 1.f / (1.f + __expf(-leak_p[h]));
  const float st = log1pf(__expf(steep_p[h]));
  const float stc = st * 1.44269504088896f;  // st * log2(e)
  const float stthr2 = stc * thr;
  const float omlk = 1.f - lk;

  // Q^T B-frags: lane holds col q = qv, d-rows 16*kk + 8*hi + i
  short8 qf[4];
#pragma unroll
  for (int kk = 0; kk < 4; ++kk)
    qf[kk] = *(const short8*)(qp + (size_t)(qbase + qv) * HD + 16 * kk + 8 * hi);

  // ---- pass A: l = sum 2^s ----
  float l_ = 0.f;
  for (int t = t0; t < t1; ++t) {
    const unsigned short* kt = kp + (size_t)t * 32 * HD;
    f32x16 sv = {};
#pragma unroll
    for (int kk = 0; kk < 4; ++kk) {
      short8 ka = *(const short8*)(kt + (size_t)qv * HD + 16 * kk + 8 * hi);
      sv = __builtin_amdgcn_mfma_f32_32x32x16_bf16(ka, qf[kk], sv, 0, 0, 0);
    }
    if (t == qt) {
#pragma unroll
      for (int j = 0; j < 16; ++j)
        if ((j & 3) + 8 * (j >> 2) + klb > qv) sv[j] = -1e30f;
    }
#pragma unroll
    for (int j = 0; j < 16; ++j) l_ += ex2(sv[j]);
  }
  l_ += __shfl_xor(l_, 32, 64);
  if (hi == 0) lbuf[s][qv] = l_;
  __syncthreads();
  const float l = (lbuf[0][qv] + lbuf[1][qv]) + (lbuf[2][qv] + lbuf[3][qv]);
  const float stli2 = stc / l;               // st * log2e / l  (per-query)

  // ---- pass B: LIF + PV (unnormalized: m = e*w, li cancels in y = O/ms) ----
  f32x16 o0 = {}, o1 = {};
  float ms = 0.f;
  for (int t = t0; t < t1; ++t) {
    const unsigned short* kt = kp + (size_t)t * 32 * HD;
    f32x16 sv = {};
#pragma unroll
    for (int kk = 0; kk < 4; ++kk) {
      short8 ka = *(const short8*)(kt + (size_t)qv * HD + 16 * kk + 8 * hi);
      sv = __builtin_amdgcn_mfma_f32_32x32x16_bf16(ka, qf[kk], sv, 0, 0, 0);
    }
    // V^T A-frags: [db][slice]: row d = db*32+qv, k = slice*16 + 8*hi + i
    short8 va00 = *(const short8*)(vp + (size_t)(qv) * TSEQ + t * 32 + 8 * hi);
    short8 va01 = *(const short8*)(vp + (size_t)(qv) * TSEQ + t * 32 + 16 + 8 * hi);
    short8 va10 = *(const short8*)(vp + (size_t)(32 + qv) * TSEQ + t * 32 + 8 * hi);
    short8 va11 = *(const short8*)(vp + (size_t)(32 + qv) * TSEQ + t * 32 + 16 + 8 * hi);

    if (t == qt) {
#pragma unroll
      for (int j = 0; j < 16; ++j)
        if ((j & 3) + 8 * (j >> 2) + klb > qv) sv[j] = -1e30f;
    }
    float mod[16];
#pragma unroll
    for (int j = 0; j < 16; ++j) {
      float e = ex2(sv[j]);
      float u = ex2(fmaf(-stli2, e, stthr2));
      float fire = __builtin_amdgcn_rcpf(1.f + u);
      float m = e * fmaf(omlk, fire, lk);
      ms += m;
      mod[j] = m;
    }
    // pack pairs (consecutive keys) to bf16
    unsigned c01 = pk2(mod[0], mod[1]),   c23 = pk2(mod[2], mod[3]);
    unsigned c45 = pk2(mod[4], mod[5]),   c67 = pk2(mod[6], mod[7]);
    unsigned c89 = pk2(mod[8], mod[9]),   cab = pk2(mod[10], mod[11]);
    unsigned ccd = pk2(mod[12], mod[13]), cef = pk2(mod[14], mod[15]);
    // cross-half exchange: send what partner needs, receive what we need
    unsigned s1 = __shfl_xor(hi ? c01 : c45, 32, 64);
    unsigned s2 = __shfl_xor(hi ? c23 : c67, 32, 64);
    unsigned s3 = __shfl_xor(hi ? c89 : ccd, 32, 64);
    unsigned s4 = __shfl_xor(hi ? cab : cef, 32, 64);
    union { unsigned u[4]; short8 v; } B0, B1;
    B0.u[0] = hi ? s1 : c01;  B0.u[1] = hi ? s2 : c23;
    B0.u[2] = hi ? c45 : s1;  B0.u[3] = hi ? c67 : s2;
    B1.u[0] = hi ? s3 : c89;  B1.u[1] = hi ? s4 : cab;
    B1.u[2] = hi ? ccd : s3;  B1.u[3] = hi ? cef : s4;

    o0 = __builtin_amdgcn_mfma_f32_32x32x16_bf16(va00, B0.v, o0, 0, 0, 0);
    o0 = __builtin_amdgcn_mfma_f32_32x32x16_bf16(va01, B1.v, o0, 0, 0, 0);
    o1 = __builtin_amdgcn_mfma_f32_32x32x16_bf16(va10, B0.v, o1, 0, 0, 0);
    o1 = __builtin_amdgcn_mfma_f32_32x32x16_bf16(va11, B1.v, o1, 0, 0, 0);
  }

  ms += __shfl_xor(ms, 32, 64);
  if (hi == 0) msbuf[s][qv] = ms;
  // accumulate O^T partials: row d_loc = (j&3)+8*(j>>2)+4*hi, col q
#pragma unroll
  for (int j = 0; j < 16; ++j) {
    const int dl = (j & 3) + 8 * (j >> 2) + klb;
    atomicAdd(&obuf[0][qv][dl], o0[j]);
    atomicAdd(&obuf[1][qv][dl], o1[j]);
  }
  __syncthreads();

  // normalize -> y
  const int d = tid & 63;
  const int db = d >> 5, dl = d & 31;
#pragma unroll
  for (int it = 0; it < 8; ++it) {
    const int q = (tid >> 6) * 8 + it;
    float acc = obuf[db][q][dl];
    float mt = ((msbuf[0][q] + msbuf[1][q]) + (msbuf[2][q] + msbuf[3][q]));
    y[((size_t)(b * TSEQ) + qbase + q) * CEMB + h * HD + d] = f2bf(acc / (mt + 1e-8f));
  }
}

extern "C" void kernel_launch(void* const* d_in, const int* in_sizes, int n_in,
                              void* d_out, int out_size, void* d_ws, size_t ws_size,
                              hipStream_t stream) {
  const float* x      = (const float*)d_in[0];
  const float* W_attn = (const float*)d_in[1];
  const float* b_attn = (const float*)d_in[2];
  const float* W_proj = (const float*)d_in[3];
  const float* b_proj = (const float*)d_in[4];
  const float* thr    = (const float*)d_in[5];
  const float* leak   = (const float*)d_in[6];
  const float* steep  = (const float*)d_in[7];
  float* out = (float*)d_out;

  unsigned short* xb   = (unsigned short*)d_ws;              // 4096x1024
  unsigned short* Wat  = xb + (size_t)4096 * 1024;           // 3072x1024
  unsigned short* Wpt  = Wat + (size_t)3072 * 1024;          // 1024x1024
  unsigned short* qws  = Wpt + (size_t)1024 * 1024;          // [32][2048][64]
  unsigned short* kws  = qws + (size_t)32 * 2048 * 64;
  unsigned short* vtws = kws + (size_t)32 * 2048 * 64;       // [32][64][2048]
  unsigned short* yb   = vtws + (size_t)32 * 2048 * 64;      // 4096x1024
  // total ~48 MB of d_ws

  castx<<<4096, 256, 0, stream>>>(x, xb);
  transW<<<dim3(48, 16), 256, 0, stream>>>(W_attn, Wat, 3072);
  transW<<<dim3(16, 16), 256, 0, stream>>>(W_proj, Wpt, 1024);
  mm128<0><<<dim3(24, 32), 256, 0, stream>>>(xb, Wat, b_attn, qws, kws, vtws);
  lif_sw<<<dim3(32, 64), 256, 0, stream>>>(qws, kws, vtws, thr, leak, steep, yb);
  mm128<1><<<dim3(8, 32), 256, 0, stream>>>(yb, Wpt, b_proj, out, nullptr, nullptr);
}

// Round 2
// 192.801 us; speedup vs baseline: 1.3090x; 1.3090x over previous
//
#include <hip/hip_runtime.h>
#include <hip/hip_bf16.h>
#include <math.h>

#define NHEAD 16
#define HD 64
#define TSEQ 2048
#define CEMB 1024

typedef __attribute__((ext_vector_type(8))) short short8;
typedef __attribute__((ext_vector_type(4))) float f32x4;
typedef __attribute__((ext_vector_type(16))) float f32x16;

__device__ inline unsigned short f2bf(float f) {
  union { float f; unsigned u; } x; x.f = f;
  unsigned r = x.u + 0x7FFFu + ((x.u >> 16) & 1u);
  return (unsigned short)(r >> 16);
}

__device__ inline unsigned pk2(float a, float b) {
  __hip_bfloat162 t = __float22bfloat162_rn(make_float2(a, b));  // low=a, high=b
  union { __hip_bfloat162 v; unsigned u; } c; c.v = t;
  return c.u;
}

// raw 2^x (v_exp_f32), no libm wrapper, no extra mul
__device__ inline float ex2(float x) {
#if __has_builtin(__builtin_amdgcn_exp2f)
  return __builtin_amdgcn_exp2f(x);
#else
  float r; asm("v_exp_f32 %0, %1" : "=v"(r) : "v"(x)); return r;
#endif
}

__device__ inline void gload16(const void* g, void* l) {
  __builtin_amdgcn_global_load_lds(
      (const __attribute__((address_space(1))) unsigned int*)g,
      (__attribute__((address_space(3))) unsigned int*)l, 16, 0, 0);
}

// ---------- cast x fp32 -> bf16 ----------
__global__ __launch_bounds__(256) void castx(const float* __restrict__ in,
                                             unsigned short* __restrict__ out) {
  int i = blockIdx.x * 256 + threadIdx.x;
  float4 v = ((const float4*)in)[i];
  ushort4 o;
  o.x = f2bf(v.x); o.y = f2bf(v.y); o.z = f2bf(v.z); o.w = f2bf(v.w);
  ((ushort4*)out)[i] = o;
}

// ---------- transpose W [1024][N] fp32 -> Wt [N][1024] bf16 ----------
__global__ __launch_bounds__(256) void transW(const float* __restrict__ W,
                                              unsigned short* __restrict__ Wt,
                                              int N) {
  __shared__ float t[64][65];
  const int tid = threadIdx.x;
  const int rb = blockIdx.y * 64;
  const int cb = blockIdx.x * 64;
#pragma unroll
  for (int i = 0; i < 16; ++i) {
    int idx = i * 256 + tid, r = idx >> 6, cl = idx & 63;
    t[r][cl] = W[(size_t)(rb + r) * N + cb + cl];
  }
  __syncthreads();
#pragma unroll
  for (int i = 0; i < 16; ++i) {
    int idx = i * 256 + tid, r = idx >> 6, cl = idx & 63;
    Wt[(size_t)(cb + r) * 1024 + rb + cl] = f2bf(t[cl][r]);
  }
}

// ---------- MFMA GEMM 128x128, BK=64, global_load_lds + XOR swizzle ----------
template <int MODE>
__global__ __launch_bounds__(256) void mm128(const unsigned short* __restrict__ A,
                                             const unsigned short* __restrict__ Bt,
                                             const float* __restrict__ bias,
                                             void* __restrict__ out0,
                                             unsigned short* __restrict__ ko,
                                             unsigned short* __restrict__ vto) {
  __shared__ __align__(16) unsigned char Asm[16384];
  __shared__ __align__(16) unsigned char Bsm[16384];
  const int tid = threadIdx.x;
  const int lane = tid & 63;
  const int w = tid >> 6;
  const int wm = w >> 1, wn = w & 1;
  const int c = lane & 15, g = lane >> 4;
  const int rowbase = blockIdx.y * 128;
  const int colbase = blockIdx.x * 128;

  f32x4 acc[4][4];
#pragma unroll
  for (int m = 0; m < 4; ++m)
#pragma unroll
    for (int n = 0; n < 4; ++n) acc[m][n] = (f32x4){0.f, 0.f, 0.f, 0.f};

  const unsigned char* Ab = (const unsigned char*)(A + (size_t)rowbase * 1024);
  const unsigned char* Bb = (const unsigned char*)(Bt + (size_t)colbase * 1024);
  const int swz = (c & 7) << 4;

  for (int kt = 0; kt < 16; ++kt) {
    __syncthreads();
#pragma unroll
    for (int it = 0; it < 4; ++it) {
      const int L = it * 4096 + tid * 16;
      const int row = L >> 7;
      const int sc = (L & 127) ^ ((row & 7) << 4);
      gload16(Ab + (size_t)row * 2048 + kt * 128 + sc, Asm + L);
      gload16(Bb + (size_t)row * 2048 + kt * 128 + sc, Bsm + L);
    }
    __syncthreads();
#pragma unroll
    for (int ks = 0; ks < 2; ++ks) {
      const int cb = ks * 64 + 16 * g;
      short8 af[4], bf[4];
#pragma unroll
      for (int m = 0; m < 4; ++m)
        af[m] = *(const short8*)(Asm + (wm * 64 + m * 16 + c) * 128 + (cb ^ swz));
#pragma unroll
      for (int n = 0; n < 4; ++n)
        bf[n] = *(const short8*)(Bsm + (wn * 64 + n * 16 + c) * 128 + (cb ^ swz));
#pragma unroll
      for (int m = 0; m < 4; ++m)
#pragma unroll
        for (int n = 0; n < 4; ++n)
          acc[m][n] = __builtin_amdgcn_mfma_f32_16x16x32_bf16(af[m], bf[n], acc[m][n], 0, 0, 0);
    }
  }

#pragma unroll
  for (int m = 0; m < 4; ++m) {
    const int rw = rowbase + wm * 64 + m * 16 + 4 * g;
#pragma unroll
    for (int n = 0; n < 4; ++n) {
      const int col = colbase + wn * 64 + n * 16 + c;
      const float bz = bias[col];
      if (MODE == 0) {
        unsigned short* qo = (unsigned short*)out0;
        const int sel = col >> 10, cc = col & 1023, hh = cc >> 6, d = cc & 63;
#pragma unroll
        for (int r = 0; r < 4; ++r) {
          const int row = rw + r;
          const int b = row >> 11, t = row & 2047;
          const float val = acc[m][n][r] + bz;
          const size_t bh = (size_t)(b * NHEAD + hh);
          if (sel == 0)
            // 0.125 * log2(e): scores arrive in log2 domain for raw v_exp_f32
            qo[(bh * TSEQ + t) * HD + d] = f2bf(val * 0.18033688011112042f);
          else if (sel == 1)
            ko[(bh * TSEQ + t) * HD + d] = f2bf(val);
          else
            vto[(bh * HD + d) * TSEQ + t] = f2bf(val);
        }
      } else {
        float* out = (float*)out0;
#pragma unroll
        for (int r = 0; r < 4; ++r)
          out[(size_t)(rw + r) * 1024 + col] = acc[m][n][r] + bz;
      }
    }
  }
}

// ---------- LIF attention, swapped-operand 32x32 in-register softmax ----------
// Block = 256 thr = 4 waves = 4 KV-splits of one 32-query tile.
// S^T = mfma(K, Q^T): lane owns query col (lane&31), 16 keys in regs.
// Scores arrive in log2 domain (Q pre-scaled by 0.125*log2e) -> raw v_exp_f32.
// Softmax normalizer li folded out: accumulate m' = e*w, ms' = sum m';
// y = O'/ms' is invariant to li.
// Split combine: per-split obuf slices + plain ds_write (NOT atomics — HIP LDS
// float atomicAdd lowers to a contended CAS loop, measured +59 us in R1).
// Cross-half P exchange via v_permlane32_swap_b32: 1 VALU instr yields both
// B-frag words, replacing 4 ds_bpermute (lgkm stall) + 8 cndmask per tile.
__global__ __launch_bounds__(256) void lif_sw(
    const unsigned short* __restrict__ qb,   // [BH][T][64] bf16, pre-scaled 0.125*log2e
    const unsigned short* __restrict__ kb,   // [BH][T][64] bf16
    const unsigned short* __restrict__ vtb,  // [BH][64][T] bf16
    const float* __restrict__ thr_p, const float* __restrict__ leak_p,
    const float* __restrict__ steep_p,
    unsigned short* __restrict__ y) {        // [B][T][1024] bf16
  __shared__ float obuf[8][32][33];          // [s*2+db][q][dl] 33.8 KB
  __shared__ float lbuf[4][32];
  __shared__ float msbuf[4][32];

  const int bh = blockIdx.x;
  const int qt = 63 - blockIdx.y;            // 32-row q tiles, big first
  const int h = bh & (NHEAD - 1);
  const int b = bh >> 4;
  const int tid = threadIdx.x;
  const int s = tid >> 6;                    // kv split 0..3
  const int lane = tid & 63;
  const int qv = lane & 31;                  // query col
  const int hi = lane >> 5;
  const int klb = 4 * hi;
  const int qbase = qt * 32;

  const int nt = qt + 1;
  const int nt4 = (nt + 3) >> 2;
  const int t0 = s * nt4;
  const int t1 = min(t0 + nt4, nt);

  const unsigned short* qp = qb + (size_t)bh * TSEQ * HD;
  const unsigned short* kp = kb + (size_t)bh * TSEQ * HD;
  const unsigned short* vp = vtb + (size_t)bh * HD * TSEQ;

  const float thr = fabsf(thr_p[h]) * 0.1f;
  const float lk = 1.f / (1.f + __expf(-leak_p[h]));
  const float st = log1pf(__expf(steep_p[h]));
  const float stc = st * 1.44269504088896f;  // st * log2(e)
  const float stthr2 = stc * thr;
  const float omlk = 1.f - lk;

  // Q^T B-frags: lane holds col q = qv, d-rows 16*kk + 8*hi + i
  short8 qf[4];
#pragma unroll
  for (int kk = 0; kk < 4; ++kk)
    qf[kk] = *(const short8*)(qp + (size_t)(qbase + qv) * HD + 16 * kk + 8 * hi);

  // ---- pass A: l = sum 2^s ----
  float l_ = 0.f;
  for (int t = t0; t < t1; ++t) {
    const unsigned short* kt = kp + (size_t)t * 32 * HD;
    f32x16 sv = {};
#pragma unroll
    for (int kk = 0; kk < 4; ++kk) {
      short8 ka = *(const short8*)(kt + (size_t)qv * HD + 16 * kk + 8 * hi);
      sv = __builtin_amdgcn_mfma_f32_32x32x16_bf16(ka, qf[kk], sv, 0, 0, 0);
    }
    if (t == qt) {
#pragma unroll
      for (int j = 0; j < 16; ++j)
        if ((j & 3) + 8 * (j >> 2) + klb > qv) sv[j] = -1e30f;
    }
#pragma unroll
    for (int j = 0; j < 16; ++j) l_ += ex2(sv[j]);
  }
  l_ += __shfl_xor(l_, 32, 64);
  if (hi == 0) lbuf[s][qv] = l_;
  __syncthreads();
  const float l = (lbuf[0][qv] + lbuf[1][qv]) + (lbuf[2][qv] + lbuf[3][qv]);
  const float stli2 = stc / l;               // st * log2e / l  (per-query)

  // ---- pass B: LIF + PV (unnormalized: m = e*w, li cancels in y = O/ms) ----
  f32x16 o0 = {}, o1 = {};
  float ms = 0.f;
  for (int t = t0; t < t1; ++t) {
    const unsigned short* kt = kp + (size_t)t * 32 * HD;
    f32x16 sv = {};
#pragma unroll
    for (int kk = 0; kk < 4; ++kk) {
      short8 ka = *(const short8*)(kt + (size_t)qv * HD + 16 * kk + 8 * hi);
      sv = __builtin_amdgcn_mfma_f32_32x32x16_bf16(ka, qf[kk], sv, 0, 0, 0);
    }
    // V^T A-frags: [db][slice]: row d = db*32+qv, k = slice*16 + 8*hi + i
    short8 va00 = *(const short8*)(vp + (size_t)(qv) * TSEQ + t * 32 + 8 * hi);
    short8 va01 = *(const short8*)(vp + (size_t)(qv) * TSEQ + t * 32 + 16 + 8 * hi);
    short8 va10 = *(const short8*)(vp + (size_t)(32 + qv) * TSEQ + t * 32 + 8 * hi);
    short8 va11 = *(const short8*)(vp + (size_t)(32 + qv) * TSEQ + t * 32 + 16 + 8 * hi);

    if (t == qt) {
#pragma unroll
      for (int j = 0; j < 16; ++j)
        if ((j & 3) + 8 * (j >> 2) + klb > qv) sv[j] = -1e30f;
    }
    float mod[16];
#pragma unroll
    for (int j = 0; j < 16; ++j) {
      float e = ex2(sv[j]);
      float u = ex2(fmaf(-stli2, e, stthr2));
      float fire = __builtin_amdgcn_rcpf(1.f + u);
      float m = e * fmaf(omlk, fire, lk);
      ms += m;
      mod[j] = m;
    }
    // pack pairs (consecutive keys) to bf16
    unsigned c01 = pk2(mod[0], mod[1]),   c23 = pk2(mod[2], mod[3]);
    unsigned c45 = pk2(mod[4], mod[5]),   c67 = pk2(mod[6], mod[7]);
    unsigned c89 = pk2(mod[8], mod[9]),   cab = pk2(mod[10], mod[11]);
    unsigned ccd = pk2(mod[12], mod[13]), cef = pk2(mod[14], mod[15]);
    // cross-half exchange: v_permlane32_swap_b32 swaps upper row of dst with
    // lower row of src -> after swap, dst = {a.lo, b.lo}, src = {a.hi, b.hi},
    // which are exactly B-frag words (w0,w2)/(w1,w3). No LDS, no selects.
    asm("v_permlane32_swap_b32 %0, %1" : "+v"(c01), "+v"(c45));
    asm("v_permlane32_swap_b32 %0, %1" : "+v"(c23), "+v"(c67));
    asm("v_permlane32_swap_b32 %0, %1" : "+v"(c89), "+v"(ccd));
    asm("v_permlane32_swap_b32 %0, %1" : "+v"(cab), "+v"(cef));
    union { unsigned u[4]; short8 v; } B0, B1;
    B0.u[0] = c01; B0.u[1] = c23; B0.u[2] = c45; B0.u[3] = c67;
    B1.u[0] = c89; B1.u[1] = cab; B1.u[2] = ccd; B1.u[3] = cef;

    o0 = __builtin_amdgcn_mfma_f32_32x32x16_bf16(va00, B0.v, o0, 0, 0, 0);
    o0 = __builtin_amdgcn_mfma_f32_32x32x16_bf16(va01, B1.v, o0, 0, 0, 0);
    o1 = __builtin_amdgcn_mfma_f32_32x32x16_bf16(va10, B0.v, o1, 0, 0, 0);
    o1 = __builtin_amdgcn_mfma_f32_32x32x16_bf16(va11, B1.v, o1, 0, 0, 0);
  }

  ms += __shfl_xor(ms, 32, 64);
  if (hi == 0) msbuf[s][qv] = ms;
  // write O^T partials: row d_loc = (j&3)+8*(j>>2)+4*hi, col q
#pragma unroll
  for (int j = 0; j < 16; ++j) {
    const int dl = (j & 3) + 8 * (j >> 2) + klb;
    obuf[s * 2 + 0][qv][dl] = o0[j];
    obuf[s * 2 + 1][qv][dl] = o1[j];
  }
  __syncthreads();

  // combine 4 splits -> normalize -> y
  const int d = tid & 63;
  const int db = d >> 5, dl = d & 31;
#pragma unroll
  for (int it = 0; it < 8; ++it) {
    const int q = (tid >> 6) * 8 + it;
    float acc = ((obuf[0 + db][q][dl] + obuf[2 + db][q][dl]) +
                 (obuf[4 + db][q][dl] + obuf[6 + db][q][dl]));
    float mt = ((msbuf[0][q] + msbuf[1][q]) + (msbuf[2][q] + msbuf[3][q]));
    y[((size_t)(b * TSEQ) + qbase + q) * CEMB + h * HD + d] = f2bf(acc / (mt + 1e-8f));
  }
}

extern "C" void kernel_launch(void* const* d_in, const int* in_sizes, int n_in,
                              void* d_out, int out_size, void* d_ws, size_t ws_size,
                              hipStream_t stream) {
  const float* x      = (const float*)d_in[0];
  const float* W_attn = (const float*)d_in[1];
  const float* b_attn = (const float*)d_in[2];
  const float* W_proj = (const float*)d_in[3];
  const float* b_proj = (const float*)d_in[4];
  const float* thr    = (const float*)d_in[5];
  const float* leak   = (const float*)d_in[6];
  const float* steep  = (const float*)d_in[7];
  float* out = (float*)d_out;

  unsigned short* xb   = (unsigned short*)d_ws;              // 4096x1024
  unsigned short* Wat  = xb + (size_t)4096 * 1024;           // 3072x1024
  unsigned short* Wpt  = Wat + (size_t)3072 * 1024;          // 1024x1024
  unsigned short* qws  = Wpt + (size_t)1024 * 1024;          // [32][2048][64]
  unsigned short* kws  = qws + (size_t)32 * 2048 * 64;
  unsigned short* vtws = kws + (size_t)32 * 2048 * 64;       // [32][64][2048]
  unsigned short* yb   = vtws + (size_t)32 * 2048 * 64;      // 4096x1024
  // total ~48 MB of d_ws

  castx<<<4096, 256, 0, stream>>>(x, xb);
  transW<<<dim3(48, 16), 256, 0, stream>>>(W_attn, Wat, 3072);
  transW<<<dim3(16, 16), 256, 0, stream>>>(W_proj, Wpt, 1024);
  mm128<0><<<dim3(24, 32), 256, 0, stream>>>(xb, Wat, b_attn, qws, kws, vtws);
  lif_sw<<<dim3(32, 64), 256, 0, stream>>>(qws, kws, vtws, thr, leak, steep, yb);
  mm128<1><<<dim3(8, 32), 256, 0, stream>>>(yb, Wpt, b_proj, out, nullptr, nullptr);
}